// Round 5
// baseline (77.856 us; speedup 1.0000x reference)
//
#include <hip/hip_runtime.h>
#include <math.h>

#define NB 2
#define NP 1200
#define NF 1000
#define IH 128
#define IW 128
#define TH 512
#define TW 512

#define TILE 8              // 8x8 pixel tiles
#define TX 16
#define TY 16
#define NTILE (TX*TY)       // 256 tiles per batch
#define CAP 1024            // per-tile list capacity (>= NF -> no overflow)

#define TPB 512             // 8 waves per raster block
#define NGRP 8
#define FCHUNK 256          // faces staged to LDS per chunk

// ws layout
#define FD_OFF   0
#define FD_BYTES (NB*NF*64)
#define CNT_OFF  FD_BYTES
#define CNT_BYTES (NB*NTILE*4)
#define LST_OFF  (CNT_OFF + CNT_BYTES)

// 64-byte per-face record: c[9], z[3] packed in floats 0..11; front at 12
struct __align__(16) FaceC {
    float c[9];
    float z[3];
    float front;
    float pad0, pad1, pad2;
};

__global__ void zero_counts(int* __restrict__ counts) {
    counts[threadIdx.x] = 0;       // NB*NTILE == 512 == blockDim
}

__global__ void prep_kernel(const float* __restrict__ points,
                            const int*  __restrict__ faces,
                            const float* __restrict__ rot,
                            const float* __restrict__ cpos,
                            const float* __restrict__ proj,
                            float* __restrict__ normal_out,
                            FaceC* __restrict__ fdata,
                            int* __restrict__ counts,
                            int* __restrict__ lists)
{
#pragma clang fp contract(off)
    int t = blockIdx.x * blockDim.x + threadIdx.x;
    if (t >= NB * NF) return;
    int b = t / NF;
    int f = t - b * NF;
    const float* R = rot + b * 9;
    float ccx = cpos[b*3+0], ccy = cpos[b*3+1], ccz = cpos[b*3+2];
    float pr0 = proj[0], pr1 = proj[1], pr2 = proj[2];

    float q[3][3];
    float sx[3], sy[3];
    for (int k = 0; k < 3; ++k) {
        int vi = faces[f*3 + k];
        const float* P = points + (b*NP + vi) * 3;
        float vx = P[0] - ccx, vy = P[1] - ccy, vz = P[2] - ccz;
        float q0 = (vx*R[0] + vy*R[1]) + vz*R[2];
        float q1 = (vx*R[3] + vy*R[4]) + vz*R[5];
        float q2 = (vx*R[6] + vy*R[7]) + vz*R[8];
        q[k][0] = q0; q[k][1] = q1; q[k][2] = q2;
        sx[k] = (q0*pr0) / (q2*pr2);   // IEEE divide, reference order
        sy[k] = (q1*pr1) / (q2*pr2);
    }

    FaceC fd;
    float x0 = sx[0], y0 = sy[0];
    float x1 = sx[1], y1 = sy[1];
    float x2 = sx[2], y2 = sy[2];
    fd.c[0] = y1 - y2;  fd.c[1] = x2 - x1;  fd.c[2] = x1*y2 - x2*y1;
    fd.c[3] = y2 - y0;  fd.c[4] = x0 - x2;  fd.c[5] = x2*y0 - x0*y2;
    fd.c[6] = y0 - y1;  fd.c[7] = x1 - x0;  fd.c[8] = x0*y1 - x1*y0;
    fd.z[0] = q[0][2]; fd.z[1] = q[1][2]; fd.z[2] = q[2][2];

    float e1x = q[1][0]-q[0][0], e1y = q[1][1]-q[0][1], e1z = q[1][2]-q[0][2];
    float e2x = q[2][0]-q[0][0], e2y = q[2][1]-q[0][1], e2z = q[2][2]-q[0][2];
    float nx = e1y*e2z - e1z*e2y;
    float ny = e1z*e2x - e1x*e2z;
    float nz = e1x*e2y - e1y*e2x;
    fd.front = (nz > 0.0f) ? 1.0f : 0.0f;
    float nlen = sqrtf(((nx*nx + ny*ny) + nz*nz) + 1e-8f);
    float nd = nlen + 1e-15f;
    normal_out[t*3+0] = nx / nd;
    normal_out[t*3+1] = ny / nd;
    normal_out[t*3+2] = nz / nd;
    fd.pad0 = fd.pad1 = fd.pad2 = 0.0f;
    fdata[t] = fd;

    // ---- binning (front faces only; back faces are dead for both outputs) ----
    if (fd.front <= 0.0f) return;

    int tx0, tx1, ty0, ty1;
    float A2 = (x1-x0)*(y2-y0) - (x2-x0)*(y1-y0);
    if (fabsf(A2) < 1e-6f) {
        tx0 = 0; ty0 = 0; tx1 = TX-1; ty1 = TY-1;   // near-degenerate: bin everywhere
    } else {
        // {min bary >= -delta} == triangle scaled by (1+3*delta) about centroid.
        // delta = 0.15 -> culled faces contribute <= sigmoid(-7.5) ~ 5.5e-4 to improb.
        const float s = 1.45f;
        float cx = (x0 + x1 + x2) * (1.0f/3.0f);
        float cy = (y0 + y1 + y2) * (1.0f/3.0f);
        float xa = cx + s*(x0-cx), xb = cx + s*(x1-cx), xc = cx + s*(x2-cx);
        float ya = cy + s*(y0-cy), yb = cy + s*(y1-cy), yc = cy + s*(y2-cy);
        float xmin = fminf(fminf(xa,xb),xc), xmax = fmaxf(fmaxf(xa,xb),xc);
        float ymin = fminf(fminf(ya,yb),yc), ymax = fmaxf(fmaxf(ya,yb),yc);
        float pxmin = (xmin + 1.0f) * (IW*0.5f) - 0.5f - 1.0f;
        float pxmax = (xmax + 1.0f) * (IW*0.5f) - 0.5f + 1.0f;
        float pymin = (1.0f - ymax) * (IH*0.5f) - 0.5f - 1.0f;
        float pymax = (1.0f - ymin) * (IH*0.5f) - 0.5f + 1.0f;
        if (pxmax < 0.0f || pymax < 0.0f || pxmin > (IW-1) || pymin > (IH-1)) return;
        int ix0 = (int)fmaxf(floorf(pxmin), 0.0f);
        int iy0 = (int)fmaxf(floorf(pymin), 0.0f);
        int ix1 = (int)fminf(ceilf(pxmax), (float)(IW-1));
        int iy1 = (int)fminf(ceilf(pymax), (float)(IH-1));
        tx0 = ix0 >> 3; tx1 = ix1 >> 3;
        ty0 = iy0 >> 3; ty1 = iy1 >> 3;
    }
    for (int ty = ty0; ty <= ty1; ++ty)
        for (int tx = tx0; tx <= tx1; ++tx) {
            int tile = b * NTILE + ty * TX + tx;
            int pos = atomicAdd(&counts[tile], 1);
            lists[tile * CAP + pos] = f;
        }
}

// LDS: face chunk (FCHUNK*16 floats = 16 KB) aliased with partials (512*9 = 18 KB)
#define LDSF 4608

__global__ __launch_bounds__(TPB) void raster_kernel(
        const FaceC* __restrict__ fdata,
        const int*  __restrict__ counts,
        const int*  __restrict__ lists,
        const float* __restrict__ tex,
        const float* __restrict__ uvp,
        const int*  __restrict__ ft,
        float* __restrict__ imrender,
        float* __restrict__ improb)
{
#pragma clang fp contract(off)
    __shared__ __align__(16) float lds[LDSF];
    __shared__ int lidx[FCHUNK];

    int b    = blockIdx.x >> 8;
    int tile = blockIdx.x & (NTILE - 1);
    int t = threadIdx.x;
    int g = t >> 6;
    int l = t & 63;
    int tx = tile & (TX - 1), ty = tile >> 4;
    int px_i = (tx << 3) | (l & 7);
    int py_i = (ty << 3) | (l >> 3);
    float px = (px_i + 0.5f) / (float)IW * 2.0f - 1.0f;
    float py = 1.0f - (py_i + 0.5f) / (float)IH * 2.0f;

    int cnt = counts[b * NTILE + tile];
    const int* list = lists + (size_t)(b * NTILE + tile) * CAP;
    const FaceC* fb = fdata + b * NF;

    float zmin = INFINITY;
    int fsel = 0x7fffffff;
    float b0s = 0.0f, b1s = 0.0f, b2s = 0.0f;
    bool covered = false;
    float maxd = -INFINITY;

    for (int base = 0; base < cnt; base += FCHUNK) {
        int c = min(FCHUNK, cnt - base);
        __syncthreads();
        // cooperative gather: 3 float4 + index per face
        for (int i = t; i < c * 4; i += TPB) {
            int j = i >> 2, q = i & 3;
            int fidx = list[base + j];
            if (q == 3) lidx[j] = fidx;
            else ((float4*)lds)[j*4 + q] = ((const float4*)(fb + fidx))[q];
        }
        __syncthreads();

        for (int j = g; j < c; j += NGRP) {
            const float4* Fv = (const float4*)(lds + j * 16);
            float4 fA = Fv[0];           // c0 c1 c2 c3
            float4 fB = Fv[1];           // c4 c5 c6 c7
            float4 fC = Fv[2];           // c8 z0 z1 z2
            float w0 = (fA.x*px + fA.y*py) + fA.z;
            float w1 = (fA.w*px + fB.x*py) + fB.y;
            float w2 = (fB.z*px + fB.w*py) + fC.x;
            float den = (w0 + w1) + w2;
            den = den + ((den >= 0.0f) ? 1e-8f : -1e-8f);
            bool sp = den > 0.0f;
            float mn = fminf(fminf(w0, w1), w2);
            float mx = fmaxf(fmaxf(w0, w1), w2);
            float wsel = sp ? mn : mx;
            float dmin = wsel * __builtin_amdgcn_rcpf(den);
            maxd = fmaxf(maxd, dmin);             // all binned faces are front
            // inside == all w_i >= 0 (sp) / all <= 0 (!sp) — via mn/mx, exact
            bool inside = sp ? (mn >= 0.0f) : (mx <= 0.0f);
            if (inside) {
                float b0 = w0 / den, b1 = w1 / den, b2 = w2 / den;  // IEEE (ref path)
                float z = (b0*fC.y + b1*fC.z) + b2*fC.w;
                int fidx = lidx[j];
                if (z < zmin || (z == zmin && fidx < fsel)) {
                    zmin = z; fsel = fidx;
                    b0s = b0; b1s = b1; b2s = b2;
                    covered = true;
                }
            }
        }
    }

    // ---- merge the 8 wave-partials via LDS (stride-9: conflict-free) ----
    __syncthreads();
    {
        float* rec = lds + t * 9;
        rec[0] = zmin;
        rec[1] = __int_as_float(fsel);
        rec[2] = b0s; rec[3] = b1s; rec[4] = b2s;
        rec[5] = maxd;
        rec[6] = __int_as_float(covered ? 1 : 0);
    }
    __syncthreads();

    if (t < 64) {
        float zb = INFINITY, rb0 = 0.0f, rb1 = 0.0f, rb2 = 0.0f;
        int fs = 0x7fffffff;
        bool cov = false;
        float md = -INFINITY;
        for (int gg = 0; gg < NGRP; ++gg) {
            const float* rec = lds + (gg * 64 + t) * 9;
            float zg = rec[0];
            int fg = __float_as_int(rec[1]);
            if (__float_as_int(rec[6]) && (zg < zb || (zg == zb && fg < fs))) {
                zb = zg; fs = fg;
                rb0 = rec[2]; rb1 = rec[3]; rb2 = rec[4];
                cov = true;
            }
            md = fmaxf(md, rec[5]);
        }

        float u = 0.0f, v = 0.0f, m = 0.0f;
        if (cov) {
            int j0 = ft[fs*3+0], j1 = ft[fs*3+1], j2 = ft[fs*3+2];
            const float* ub = uvp + (size_t)b * NP * 2;
            u = (rb0*ub[j0*2+0] + rb1*ub[j1*2+0]) + rb2*ub[j2*2+0];
            v = (rb0*ub[j0*2+1] + rb1*ub[j1*2+1]) + rb2*ub[j2*2+1];
            m = (rb0 + rb1) + rb2;
        }

        float gu = (u - floorf(u)) * 2.0f - 1.0f;
        float gv = (v - floorf(v)) * 2.0f - 1.0f;
        gv = -gv;
        float ix = ((gu + 1.0f) * (float)TW - 1.0f) * 0.5f;
        float iy = ((gv + 1.0f) * (float)TH - 1.0f) * 0.5f;
        float ixr = rintf(ix);
        float iyr = rintf(iy);
        int ixn = (int)ixr, iyn = (int)iyr;
        bool tvalid = (ixn >= 0) && (ixn < TW) && (iyn >= 0) && (iyn < TH);
        int ixc = min(max(ixn, 0), TW-1);
        int iyc = min(max(iyn, 0), TH-1);
        float vmul = tvalid ? 1.0f : 0.0f;
        const float* tb = tex + (size_t)b * 3 * TH * TW;
        float tr  = tb[(0*TH + iyc)*TW + ixc] * vmul;
        float tg  = tb[(1*TH + iyc)*TW + ixc] * vmul;
        float tb2 = tb[(2*TH + iyc)*TW + ixc] * vmul;

        float o0 = fminf(fmaxf(tr  * m, 0.0f), 1.0f);
        float o1 = fminf(fmaxf(tg  * m, 0.0f), 1.0f);
        float o2 = fminf(fmaxf(tb2 * m, 0.0f), 1.0f);

        float pr = 0.0f;
        if (cnt > 0) {
            float sxv = md / 0.02f;
            if (sxv >= 0.0f) pr = 1.0f / (1.0f + expf(-sxv));
            else { float e = expf(sxv); pr = e / (1.0f + e); }
        }

        int ppx = (tx << 3) | (t & 7);
        int ppy = (ty << 3) | (t >> 3);
        int pix = b * (IH*IW) + ppy * IW + ppx;
        float* outp = imrender + (size_t)pix * 3;
        outp[0] = o0; outp[1] = o1; outp[2] = o2;
        improb[pix] = pr;
    }
}

extern "C" void kernel_launch(void* const* d_in, const int* in_sizes, int n_in,
                              void* d_out, int out_size, void* d_ws, size_t ws_size,
                              hipStream_t stream) {
    const float* points = (const float*)d_in[0];
    const int*   faces  = (const int*)  d_in[1];
    const float* rot    = (const float*)d_in[2];
    const float* cpos   = (const float*)d_in[3];
    const float* proj   = (const float*)d_in[4];
    const float* uvp    = (const float*)d_in[5];
    const float* tex    = (const float*)d_in[6];
    const int*   ft     = (const int*)  d_in[7];

    float* out        = (float*)d_out;
    float* imrender   = out;
    float* improb     = out + NB*IH*IW*3;
    float* normal_out = out + NB*IH*IW*3 + NB*IH*IW;

    char*  ws     = (char*)d_ws;
    FaceC* fdata  = (FaceC*)(ws + FD_OFF);
    int*   counts = (int*)  (ws + CNT_OFF);
    int*   lists  = (int*)  (ws + LST_OFF);

    zero_counts<<<1, NB*NTILE, 0, stream>>>(counts);
    prep_kernel<<<(NB*NF + 255)/256, 256, 0, stream>>>(
        points, faces, rot, cpos, proj, normal_out, fdata, counts, lists);
    raster_kernel<<<NB*NTILE, TPB, 0, stream>>>(
        fdata, counts, lists, tex, uvp, ft, imrender, improb);
}

// Round 6
// 42.414 us; speedup vs baseline: 1.8356x; 1.8356x over previous
//
#include <hip/hip_runtime.h>
#include <math.h>

#define NB 2
#define NP 1200
#define NF 1000
#define IH 128
#define IW 128
#define TH 512
#define TW 512

#define TILE 8
#define TX 16
#define TY 16
#define NTILE (TX*TY)       // 256 tiles per batch

#define TPB 512             // 8 waves per raster block
#define NGRP 8
#define FCHUNK 256          // faces staged to LDS per chunk

// ws layout: 48B c/z records, then dense bboxes
#define FG_OFF   0
#define FG_BYTES (NB*NF*48)              // 96000
#define BB_OFF   ((FG_BYTES + 15) & ~15)
// bbox: NB*NF float4 = 32000 B

// 48-byte record: 3 float4 = [c0..c3][c4..c7][c8,z0,z1,z2]
struct __align__(16) FaceG {
    float4 A, B, C;
};

__global__ void prep_kernel(const float* __restrict__ points,
                            const int*  __restrict__ faces,
                            const float* __restrict__ rot,
                            const float* __restrict__ cpos,
                            const float* __restrict__ proj,
                            float* __restrict__ normal_out,
                            FaceG* __restrict__ fg,
                            float4* __restrict__ bbox)
{
#pragma clang fp contract(off)
    int t = blockIdx.x * blockDim.x + threadIdx.x;
    if (t >= NB * NF) return;
    int b = t / NF;
    int f = t - b * NF;
    const float* R = rot + b * 9;
    float ccx = cpos[b*3+0], ccy = cpos[b*3+1], ccz = cpos[b*3+2];
    float pr0 = proj[0], pr1 = proj[1], pr2 = proj[2];

    float q[3][3];
    float sx[3], sy[3];
    for (int k = 0; k < 3; ++k) {
        int vi = faces[f*3 + k];
        const float* P = points + (b*NP + vi) * 3;
        float vx = P[0] - ccx, vy = P[1] - ccy, vz = P[2] - ccz;
        float q0 = (vx*R[0] + vy*R[1]) + vz*R[2];
        float q1 = (vx*R[3] + vy*R[4]) + vz*R[5];
        float q2 = (vx*R[6] + vy*R[7]) + vz*R[8];
        q[k][0] = q0; q[k][1] = q1; q[k][2] = q2;
        sx[k] = (q0*pr0) / (q2*pr2);   // IEEE divide, reference order
        sy[k] = (q1*pr1) / (q2*pr2);
    }

    float x0 = sx[0], y0 = sy[0];
    float x1 = sx[1], y1 = sy[1];
    float x2 = sx[2], y2 = sy[2];
    FaceG rec;
    rec.A = make_float4(y1 - y2, x2 - x1, x1*y2 - x2*y1, y2 - y0);
    rec.B = make_float4(x0 - x2, x2*y0 - x0*y2, y0 - y1, x1 - x0);
    rec.C = make_float4(x0*y1 - x1*y0, q[0][2], q[1][2], q[2][2]);
    fg[t] = rec;

    float e1x = q[1][0]-q[0][0], e1y = q[1][1]-q[0][1], e1z = q[1][2]-q[0][2];
    float e2x = q[2][0]-q[0][0], e2y = q[2][1]-q[0][1], e2z = q[2][2]-q[0][2];
    float nx = e1y*e2z - e1z*e2y;
    float ny = e1z*e2x - e1x*e2z;
    float nz = e1x*e2y - e1y*e2x;
    bool front = nz > 0.0f;
    float nlen = sqrtf(((nx*nx + ny*ny) + nz*nz) + 1e-8f);
    float nd = nlen + 1e-15f;
    normal_out[t*3+0] = nx / nd;
    normal_out[t*3+1] = ny / nd;
    normal_out[t*3+2] = nz / nd;

    // ---- conservative pixel-space bbox (xmin, ymin, xmax, ymax) ----
    float4 bb;
    if (!front) {
        bb = make_float4(1e9f, 1e9f, -1e9f, -1e9f);            // empty: culled everywhere
    } else {
        float A2 = (x1-x0)*(y2-y0) - (x2-x0)*(y1-y0);
        if (fabsf(A2) < 1e-6f) {
            bb = make_float4(-1e9f, -1e9f, 1e9f, 1e9f);        // degenerate: everywhere
        } else {
            // {min bary >= -delta} == triangle scaled by (1+3*delta) about centroid.
            // delta = 0.15 -> culled faces contribute <= sigmoid(-7.5) ~ 5.5e-4.
            const float s = 1.45f;
            float cx = (x0 + x1 + x2) * (1.0f/3.0f);
            float cy = (y0 + y1 + y2) * (1.0f/3.0f);
            float xa = cx + s*(x0-cx), xb = cx + s*(x1-cx), xc = cx + s*(x2-cx);
            float ya = cy + s*(y0-cy), yb = cy + s*(y1-cy), yc = cy + s*(y2-cy);
            float xmin = fminf(fminf(xa,xb),xc), xmax = fmaxf(fmaxf(xa,xb),xc);
            float ymin = fminf(fminf(ya,yb),yc), ymax = fmaxf(fmaxf(ya,yb),yc);
            // NDC -> pixel index space (+1px safety for fp rounding)
            bb.x = (xmin + 1.0f) * (IW*0.5f) - 0.5f - 1.0f;    // pxmin
            bb.z = (xmax + 1.0f) * (IW*0.5f) - 0.5f + 1.0f;    // pxmax
            bb.y = (1.0f - ymax) * (IH*0.5f) - 0.5f - 1.0f;    // pymin
            bb.w = (1.0f - ymin) * (IH*0.5f) - 0.5f + 1.0f;    // pymax
        }
    }
    bbox[t] = bb;
}

// LDS: survivor list (NF ints) + staging (FCHUNK*12 floats) aliased with partials (512*9)
#define SMEMF 4608   // max(FCHUNK*12=3072, TPB*9=4608) floats

__global__ __launch_bounds__(TPB) void raster_kernel(
        const FaceG* __restrict__ fdata,
        const float4* __restrict__ bbox,
        const float* __restrict__ tex,
        const float* __restrict__ uvp,
        const int*  __restrict__ ft,
        float* __restrict__ imrender,
        float* __restrict__ improb)
{
#pragma clang fp contract(off)
    __shared__ __align__(16) float smem[SMEMF];
    __shared__ int llist[NF];
    __shared__ int lcnt;

    int b    = blockIdx.x >> 8;
    int tile = blockIdx.x & (NTILE - 1);
    int t = threadIdx.x;
    int g = t >> 6;
    int l = t & 63;
    int tx = tile & (TX - 1), ty = tile >> 4;
    int px_i = (tx << 3) | (l & 7);
    int py_i = (ty << 3) | (l >> 3);
    float px = (px_i + 0.5f) / (float)IW * 2.0f - 1.0f;
    float py = 1.0f - (py_i + 0.5f) / (float)IH * 2.0f;

    // tile pixel rect (floats) for the overlap test
    float txlo = (float)(tx << 3), txhi = (float)((tx << 3) + 7);
    float tylo = (float)(ty << 3), tyhi = (float)((ty << 3) + 7);

    if (t == 0) lcnt = 0;
    __syncthreads();

    // ---- phase A: cull 1000 faces against this tile (coalesced bbox reads) ----
    const float4* bbb = bbox + b * NF;
    for (int i = t; i < NF; i += TPB) {
        float4 bb = bbb[i];
        bool ov = (bb.x <= txhi) & (bb.z >= txlo) & (bb.y <= tyhi) & (bb.w >= tylo);
        if (ov) {
            int p = atomicAdd(&lcnt, 1);
            llist[p] = i;
        }
    }
    __syncthreads();
    int cnt = lcnt;
    const FaceG* fb = fdata + b * NF;

    float zmin = INFINITY;
    int fsel = 0x7fffffff;
    float b0s = 0.0f, b1s = 0.0f, b2s = 0.0f;
    bool covered = false;
    float maxd = -INFINITY;

    for (int base = 0; base < cnt; base += FCHUNK) {
        int c = min(FCHUNK, cnt - base);
        __syncthreads();
        // cooperative gather: 3 float4 per face
        for (int i = t; i < c * 3; i += TPB) {
            int j = i / 3, q = i - j * 3;
            int fidx = llist[base + j];
            ((float4*)smem)[j*3 + q] = ((const float4*)(fb + fidx))[q];
        }
        __syncthreads();

        for (int j = g; j < c; j += NGRP) {
            const float4* Fv = (const float4*)(smem + j * 12);
            float4 fA = Fv[0];           // c0 c1 c2 c3
            float4 fB = Fv[1];           // c4 c5 c6 c7
            float4 fC = Fv[2];           // c8 z0 z1 z2
            float w0 = (fA.x*px + fA.y*py) + fA.z;
            float w1 = (fA.w*px + fB.x*py) + fB.y;
            float w2 = (fB.z*px + fB.w*py) + fC.x;
            float den = (w0 + w1) + w2;
            den = den + ((den >= 0.0f) ? 1e-8f : -1e-8f);
            bool sp = den > 0.0f;
            float mn = fminf(fminf(w0, w1), w2);
            float mx = fmaxf(fmaxf(w0, w1), w2);
            float wsel = sp ? mn : mx;
            float dmin = wsel * __builtin_amdgcn_rcpf(den);
            maxd = fmaxf(maxd, dmin);             // all surviving faces are front
            bool inside = sp ? (mn >= 0.0f) : (mx <= 0.0f);
            if (inside) {
                float b0 = w0 / den, b1 = w1 / den, b2 = w2 / den;  // IEEE (ref path)
                float z = (b0*fC.y + b1*fC.z) + b2*fC.w;
                int fidx = llist[base + j];
                if (z < zmin || (z == zmin && fidx < fsel)) {
                    zmin = z; fsel = fidx;
                    b0s = b0; b1s = b1; b2s = b2;
                    covered = true;
                }
            }
        }
    }

    // ---- merge the 8 wave-partials via LDS (stride-9: conflict-free) ----
    __syncthreads();
    {
        float* rec = smem + t * 9;
        rec[0] = zmin;
        rec[1] = __int_as_float(fsel);
        rec[2] = b0s; rec[3] = b1s; rec[4] = b2s;
        rec[5] = maxd;
        rec[6] = __int_as_float(covered ? 1 : 0);
    }
    __syncthreads();

    if (t < 64) {
        float zb = INFINITY, rb0 = 0.0f, rb1 = 0.0f, rb2 = 0.0f;
        int fs = 0x7fffffff;
        bool cov = false;
        float md = -INFINITY;
        for (int gg = 0; gg < NGRP; ++gg) {
            const float* rec = smem + (gg * 64 + t) * 9;
            float zg = rec[0];
            int fg_ = __float_as_int(rec[1]);
            if (__float_as_int(rec[6]) && (zg < zb || (zg == zb && fg_ < fs))) {
                zb = zg; fs = fg_;
                rb0 = rec[2]; rb1 = rec[3]; rb2 = rec[4];
                cov = true;
            }
            md = fmaxf(md, rec[5]);
        }

        float u = 0.0f, v = 0.0f, m = 0.0f;
        if (cov) {
            int j0 = ft[fs*3+0], j1 = ft[fs*3+1], j2 = ft[fs*3+2];
            const float* ub = uvp + (size_t)b * NP * 2;
            u = (rb0*ub[j0*2+0] + rb1*ub[j1*2+0]) + rb2*ub[j2*2+0];
            v = (rb0*ub[j0*2+1] + rb1*ub[j1*2+1]) + rb2*ub[j2*2+1];
            m = (rb0 + rb1) + rb2;
        }

        float gu = (u - floorf(u)) * 2.0f - 1.0f;
        float gv = (v - floorf(v)) * 2.0f - 1.0f;
        gv = -gv;
        float ix = ((gu + 1.0f) * (float)TW - 1.0f) * 0.5f;
        float iy = ((gv + 1.0f) * (float)TH - 1.0f) * 0.5f;
        float ixr = rintf(ix);
        float iyr = rintf(iy);
        int ixn = (int)ixr, iyn = (int)iyr;
        bool tvalid = (ixn >= 0) && (ixn < TW) && (iyn >= 0) && (iyn < TH);
        int ixc = min(max(ixn, 0), TW-1);
        int iyc = min(max(iyn, 0), TH-1);
        float vmul = tvalid ? 1.0f : 0.0f;
        const float* tb = tex + (size_t)b * 3 * TH * TW;
        float tr  = tb[(0*TH + iyc)*TW + ixc] * vmul;
        float tg  = tb[(1*TH + iyc)*TW + ixc] * vmul;
        float tb2 = tb[(2*TH + iyc)*TW + ixc] * vmul;

        float o0 = fminf(fmaxf(tr  * m, 0.0f), 1.0f);
        float o1 = fminf(fmaxf(tg  * m, 0.0f), 1.0f);
        float o2 = fminf(fmaxf(tb2 * m, 0.0f), 1.0f);

        float pr = 0.0f;
        if (cnt > 0) {
            float sxv = md / 0.02f;
            if (sxv >= 0.0f) pr = 1.0f / (1.0f + expf(-sxv));
            else { float e = expf(sxv); pr = e / (1.0f + e); }
        }

        int ppx = (tx << 3) | (t & 7);
        int ppy = (ty << 3) | (t >> 3);
        int pix = b * (IH*IW) + ppy * IW + ppx;
        float* outp = imrender + (size_t)pix * 3;
        outp[0] = o0; outp[1] = o1; outp[2] = o2;
        improb[pix] = pr;
    }
}

extern "C" void kernel_launch(void* const* d_in, const int* in_sizes, int n_in,
                              void* d_out, int out_size, void* d_ws, size_t ws_size,
                              hipStream_t stream) {
    const float* points = (const float*)d_in[0];
    const int*   faces  = (const int*)  d_in[1];
    const float* rot    = (const float*)d_in[2];
    const float* cpos   = (const float*)d_in[3];
    const float* proj   = (const float*)d_in[4];
    const float* uvp    = (const float*)d_in[5];
    const float* tex    = (const float*)d_in[6];
    const int*   ft     = (const int*)  d_in[7];

    float* out        = (float*)d_out;
    float* imrender   = out;
    float* improb     = out + NB*IH*IW*3;
    float* normal_out = out + NB*IH*IW*3 + NB*IH*IW;

    char*   ws    = (char*)d_ws;
    FaceG*  fg    = (FaceG*) (ws + FG_OFF);
    float4* bbox  = (float4*)(ws + BB_OFF);

    prep_kernel<<<(NB*NF + 255)/256, 256, 0, stream>>>(
        points, faces, rot, cpos, proj, normal_out, fg, bbox);
    raster_kernel<<<NB*NTILE, TPB, 0, stream>>>(
        fg, bbox, tex, uvp, ft, imrender, improb);
}

// Round 7
// 40.849 us; speedup vs baseline: 1.9060x; 1.0383x over previous
//
#include <hip/hip_runtime.h>
#include <math.h>

#define NB 2
#define NP 1200
#define NF 1000
#define IH 128
#define IW 128
#define TH 512
#define TW 512

#define TX 16
#define TY 16
#define NTILE (TX*TY)       // 256 tiles per batch
#define TPB 512             // 8 waves per block
#define NGRP 8

// Single fused kernel: one block per 8x8 tile. Each block recomputes all
// NF face records into LDS (cheap, fully parallel, L2-resident inputs),
// culls against its own tile, rasterizes, and shades. No workspace at all.
__global__ __launch_bounds__(TPB) void render_kernel(
        const float* __restrict__ points,
        const int*  __restrict__ faces,
        const float* __restrict__ rot,
        const float* __restrict__ cpos,
        const float* __restrict__ proj,
        const float* __restrict__ uvp,
        const float* __restrict__ tex,
        const int*  __restrict__ ft,
        float* __restrict__ imrender,
        float* __restrict__ improb,
        float* __restrict__ normal_out)
{
#pragma clang fp contract(off)
    // records: NF * 12 floats = 48000 B; partials (512*9=4608 floats) alias it
    __shared__ __align__(16) float recs[NF * 12];
    __shared__ int llist[NF];
    __shared__ int lcnt;

    int b    = blockIdx.x >> 8;
    int tile = blockIdx.x & (NTILE - 1);
    int t = threadIdx.x;
    int g = t >> 6;
    int l = t & 63;
    int tx = tile & (TX - 1), ty = tile >> 4;
    int px_i = (tx << 3) | (l & 7);
    int py_i = (ty << 3) | (l >> 3);
    float px = (px_i + 0.5f) / (float)IW * 2.0f - 1.0f;
    float py = 1.0f - (py_i + 0.5f) / (float)IH * 2.0f;

    // tile pixel rect for the conservative overlap test
    float txlo = (float)(tx << 3), txhi = (float)((tx << 3) + 7);
    float tylo = (float)(ty << 3), tyhi = (float)((ty << 3) + 7);

    if (t == 0) lcnt = 0;
    __syncthreads();

    // ---- phase A: per-block face prep + cull (all NF faces, 512-thread parallel) ----
    {
        const float* R = rot + b * 9;
        float ccx = cpos[b*3+0], ccy = cpos[b*3+1], ccz = cpos[b*3+2];
        float pr0 = proj[0], pr1 = proj[1], pr2 = proj[2];

        for (int f = t; f < NF; f += TPB) {
            float q2s[3], sx[3], sy[3];
            float qx[3], qy[3];
            for (int k = 0; k < 3; ++k) {
                int vi = faces[f*3 + k];
                const float* P = points + (b*NP + vi) * 3;
                float vx = P[0] - ccx, vy = P[1] - ccy, vz = P[2] - ccz;
                float q0 = (vx*R[0] + vy*R[1]) + vz*R[2];
                float q1 = (vx*R[3] + vy*R[4]) + vz*R[5];
                float q2 = (vx*R[6] + vy*R[7]) + vz*R[8];
                qx[k] = q0; qy[k] = q1; q2s[k] = q2;
                sx[k] = (q0*pr0) / (q2*pr2);   // IEEE divide, reference order
                sy[k] = (q1*pr1) / (q2*pr2);
            }
            float x0 = sx[0], y0 = sy[0];
            float x1 = sx[1], y1 = sy[1];
            float x2 = sx[2], y2 = sy[2];

            float4* rp = (float4*)(recs + f * 12);
            rp[0] = make_float4(y1 - y2, x2 - x1, x1*y2 - x2*y1, y2 - y0);
            rp[1] = make_float4(x0 - x2, x2*y0 - x0*y2, y0 - y1, x1 - x0);
            rp[2] = make_float4(x0*y1 - x1*y0, q2s[0], q2s[1], q2s[2]);

            float e1x = qx[1]-qx[0], e1y = qy[1]-qy[0], e1z = q2s[1]-q2s[0];
            float e2x = qx[2]-qx[0], e2y = qy[2]-qy[0], e2z = q2s[2]-q2s[0];
            float nx = e1y*e2z - e1z*e2y;
            float ny = e1z*e2x - e1x*e2z;
            float nz = e1x*e2y - e1y*e2x;
            bool front = nz > 0.0f;

            if (tile == 0) {   // block-uniform: tile-0 block of each batch writes normals
                float nlen = sqrtf(((nx*nx + ny*ny) + nz*nz) + 1e-8f);
                float nd = nlen + 1e-15f;
                int o = (b*NF + f) * 3;
                normal_out[o+0] = nx / nd;
                normal_out[o+1] = ny / nd;
                normal_out[o+2] = nz / nd;
            }

            // conservative cull vs this tile
            bool keep = false;
            if (front) {
                float A2 = (x1-x0)*(y2-y0) - (x2-x0)*(y1-y0);
                if (fabsf(A2) < 1e-6f) {
                    keep = true;   // near-degenerate: keep everywhere
                } else {
                    // {min bary >= -delta} == triangle scaled by (1+3*delta) about
                    // centroid; delta=0.15 -> culled faces contribute <= 5.5e-4.
                    const float s = 1.45f;
                    float cx = (x0 + x1 + x2) * (1.0f/3.0f);
                    float cy = (y0 + y1 + y2) * (1.0f/3.0f);
                    float xa = cx + s*(x0-cx), xb = cx + s*(x1-cx), xc = cx + s*(x2-cx);
                    float ya = cy + s*(y0-cy), yb = cy + s*(y1-cy), yc = cy + s*(y2-cy);
                    float xmin = fminf(fminf(xa,xb),xc), xmax = fmaxf(fmaxf(xa,xb),xc);
                    float ymin = fminf(fminf(ya,yb),yc), ymax = fmaxf(fmaxf(ya,yb),yc);
                    float pxmin = (xmin + 1.0f) * (IW*0.5f) - 0.5f - 1.0f;
                    float pxmax = (xmax + 1.0f) * (IW*0.5f) - 0.5f + 1.0f;
                    float pymin = (1.0f - ymax) * (IH*0.5f) - 0.5f - 1.0f;
                    float pymax = (1.0f - ymin) * (IH*0.5f) - 0.5f + 1.0f;
                    keep = (pxmin <= txhi) & (pxmax >= txlo) &
                           (pymin <= tyhi) & (pymax >= tylo);
                }
            }
            if (keep) {
                int p = atomicAdd(&lcnt, 1);
                llist[p] = f;
            }
        }
    }
    __syncthreads();
    int cnt = lcnt;

    // ---- phase B: rasterize this tile's survivor list (LDS broadcast reads) ----
    float zmin = INFINITY;
    int fsel = 0x7fffffff;
    float b0s = 0.0f, b1s = 0.0f, b2s = 0.0f;
    bool covered = false;
    float maxd = -INFINITY;

    for (int j = g; j < cnt; j += NGRP) {
        int fidx = llist[j];                       // wave-uniform
        const float4* Fv = (const float4*)(recs + fidx * 12);
        float4 fA = Fv[0];           // c0 c1 c2 c3
        float4 fB = Fv[1];           // c4 c5 c6 c7
        float4 fC = Fv[2];           // c8 z0 z1 z2
        float w0 = (fA.x*px + fA.y*py) + fA.z;
        float w1 = (fA.w*px + fB.x*py) + fB.y;
        float w2 = (fB.z*px + fB.w*py) + fC.x;
        float den = (w0 + w1) + w2;
        den = den + ((den >= 0.0f) ? 1e-8f : -1e-8f);
        bool sp = den > 0.0f;
        float mn = fminf(fminf(w0, w1), w2);
        float mx = fmaxf(fmaxf(w0, w1), w2);
        float wsel = sp ? mn : mx;
        float dmin = wsel * __builtin_amdgcn_rcpf(den);
        maxd = fmaxf(maxd, dmin);             // all surviving faces are front
        bool inside = sp ? (mn >= 0.0f) : (mx <= 0.0f);
        if (inside) {
            float b0 = w0 / den, b1 = w1 / den, b2 = w2 / den;  // IEEE (ref path)
            float z = (b0*fC.y + b1*fC.z) + b2*fC.w;
            if (z < zmin || (z == zmin && fidx < fsel)) {       // order-independent
                zmin = z; fsel = fidx;
                b0s = b0; b1s = b1; b2s = b2;
                covered = true;
            }
        }
    }

    // ---- merge the 8 wave-partials (stride-9 alias over recs: conflict-free) ----
    __syncthreads();
    {
        float* rec = recs + t * 9;
        rec[0] = zmin;
        rec[1] = __int_as_float(fsel);
        rec[2] = b0s; rec[3] = b1s; rec[4] = b2s;
        rec[5] = maxd;
        rec[6] = __int_as_float(covered ? 1 : 0);
    }
    __syncthreads();

    if (t < 64) {
        float zb = INFINITY, rb0 = 0.0f, rb1 = 0.0f, rb2 = 0.0f;
        int fs = 0x7fffffff;
        bool cov = false;
        float md = -INFINITY;
        for (int gg = 0; gg < NGRP; ++gg) {
            const float* rec = recs + (gg * 64 + t) * 9;
            float zg = rec[0];
            int fg_ = __float_as_int(rec[1]);
            if (__float_as_int(rec[6]) && (zg < zb || (zg == zb && fg_ < fs))) {
                zb = zg; fs = fg_;
                rb0 = rec[2]; rb1 = rec[3]; rb2 = rec[4];
                cov = true;
            }
            md = fmaxf(md, rec[5]);
        }

        float u = 0.0f, v = 0.0f, m = 0.0f;
        if (cov) {
            int j0 = ft[fs*3+0], j1 = ft[fs*3+1], j2 = ft[fs*3+2];
            const float* ub = uvp + (size_t)b * NP * 2;
            u = (rb0*ub[j0*2+0] + rb1*ub[j1*2+0]) + rb2*ub[j2*2+0];
            v = (rb0*ub[j0*2+1] + rb1*ub[j1*2+1]) + rb2*ub[j2*2+1];
            m = (rb0 + rb1) + rb2;
        }

        float gu = (u - floorf(u)) * 2.0f - 1.0f;
        float gv = (v - floorf(v)) * 2.0f - 1.0f;
        gv = -gv;
        float ix = ((gu + 1.0f) * (float)TW - 1.0f) * 0.5f;
        float iy = ((gv + 1.0f) * (float)TH - 1.0f) * 0.5f;
        float ixr = rintf(ix);   // round-half-even == jnp.round
        float iyr = rintf(iy);
        int ixn = (int)ixr, iyn = (int)iyr;
        bool tvalid = (ixn >= 0) && (ixn < TW) && (iyn >= 0) && (iyn < TH);
        int ixc = min(max(ixn, 0), TW-1);
        int iyc = min(max(iyn, 0), TH-1);
        float vmul = tvalid ? 1.0f : 0.0f;
        const float* tb = tex + (size_t)b * 3 * TH * TW;
        float tr  = tb[(0*TH + iyc)*TW + ixc] * vmul;
        float tg  = tb[(1*TH + iyc)*TW + ixc] * vmul;
        float tb2 = tb[(2*TH + iyc)*TW + ixc] * vmul;

        float o0 = fminf(fmaxf(tr  * m, 0.0f), 1.0f);
        float o1 = fminf(fmaxf(tg  * m, 0.0f), 1.0f);
        float o2 = fminf(fmaxf(tb2 * m, 0.0f), 1.0f);

        float pr = 0.0f;
        if (cnt > 0) {
            float sxv = md / 0.02f;
            if (sxv >= 0.0f) pr = 1.0f / (1.0f + expf(-sxv));
            else { float e = expf(sxv); pr = e / (1.0f + e); }
        }

        int ppx = (tx << 3) | (t & 7);
        int ppy = (ty << 3) | (t >> 3);
        int pix = b * (IH*IW) + ppy * IW + ppx;
        float* outp = imrender + (size_t)pix * 3;
        outp[0] = o0; outp[1] = o1; outp[2] = o2;
        improb[pix] = pr;
    }
}

extern "C" void kernel_launch(void* const* d_in, const int* in_sizes, int n_in,
                              void* d_out, int out_size, void* d_ws, size_t ws_size,
                              hipStream_t stream) {
    const float* points = (const float*)d_in[0];
    const int*   faces  = (const int*)  d_in[1];
    const float* rot    = (const float*)d_in[2];
    const float* cpos   = (const float*)d_in[3];
    const float* proj   = (const float*)d_in[4];
    const float* uvp    = (const float*)d_in[5];
    const float* tex    = (const float*)d_in[6];
    const int*   ft     = (const int*)  d_in[7];

    float* out        = (float*)d_out;
    float* imrender   = out;
    float* improb     = out + NB*IH*IW*3;
    float* normal_out = out + NB*IH*IW*3 + NB*IH*IW;

    // single dispatch, zero workspace usage
    render_kernel<<<NB*NTILE, TPB, 0, stream>>>(
        points, faces, rot, cpos, proj, uvp, tex, ft,
        imrender, improb, normal_out);
}